// Round 4
// baseline (685.089 us; speedup 1.0000x reference)
//
#include <hip/hip_runtime.h>
#include <math.h>

// ---------------------------------------------------------------------------
// GAT 3-layer + pooling.
//  - GEMMs: fp16 MFMA 128x128x32; layer-2's two GEMMs fused into one N=1536.
//  - Aggregation: persistent grid-stride waves (2048 blocks = full residency),
//    one wave per node, all heads fused; edge-parallel weight phase into LDS,
//    channel-parallel gather phase with wide aligned loads.
//    Bound by per-CU outstanding-miss concurrency -> maximize resident waves.
// ---------------------------------------------------------------------------

typedef _Float16 f16;
typedef __attribute__((ext_vector_type(8))) _Float16 half8;
typedef __attribute__((ext_vector_type(4))) _Float16 half4;
typedef __attribute__((ext_vector_type(2))) _Float16 half2v;
typedef __attribute__((ext_vector_type(4))) float float4v;

#define M_PAD 20096        // 20000 rounded up to 128
#define AGG_BLOCKS 2048    // 8 blocks/CU * 256 CUs
#define AGG_WAVES (AGG_BLOCKS * 4)

__device__ inline void gload_lds16(const void* g, void* l) {
    __builtin_amdgcn_global_load_lds((const __attribute__((address_space(1))) unsigned*)g,
                                     (__attribute__((address_space(3))) unsigned*)l,
                                     16, 0, 0);
}

// ----------------------------- CSR construction ---------------------------

__global__ __launch_bounds__(256) void deg_kernel(const int* __restrict__ dst,
                                                  int* __restrict__ deg, int E) {
    int e = blockIdx.x * 256 + threadIdx.x;
    if (e < E) atomicAdd(&deg[dst[e]], 1);
}

__global__ __launch_bounds__(1024) void scan_kernel(const int* __restrict__ deg,
                                                    int* __restrict__ row_off, int n) {
    __shared__ int sums[1024];
    int t = threadIdx.x;
    int CH = (n + 1023) >> 10;
    int base = t * CH;
    int s = 0;
    for (int i = 0; i < CH; ++i) { int idx = base + i; if (idx < n) s += deg[idx]; }
    sums[t] = s;
    __syncthreads();
    for (int off = 1; off < 1024; off <<= 1) {
        int v = (t >= off) ? sums[t - off] : 0;
        __syncthreads();
        sums[t] += v;
        __syncthreads();
    }
    int run = (t == 0) ? 0 : sums[t - 1];
    for (int i = 0; i < CH; ++i) {
        int idx = base + i;
        if (idx < n) { row_off[idx] = run; run += deg[idx]; }
    }
    if (t == 1023) row_off[n] = run;
}

__global__ __launch_bounds__(256) void fill_kernel(const int* __restrict__ src,
                                                   const int* __restrict__ dst,
                                                   const int* __restrict__ row_off,
                                                   int* __restrict__ fill,
                                                   int* __restrict__ csr_src, int E) {
    int e = blockIdx.x * 256 + threadIdx.x;
    if (e < E) {
        int d = dst[e];
        int pos = row_off[d] + atomicAdd(&fill[d], 1);
        csr_src[pos] = src[e];
    }
}

// ------------------------------ converts -----------------------------------

__global__ __launch_bounds__(256) void cvt_pad_kernel(const float* __restrict__ x,
                                                      f16* __restrict__ y,
                                                      long n_valid, long n_total) {
    long i = ((long)blockIdx.x * 256 + threadIdx.x) * 4;
    if (i >= n_total) return;
    float4 v = make_float4(0.f, 0.f, 0.f, 0.f);
    if (i < n_valid) v = *(const float4*)&x[i];
    half4 o; o[0] = (f16)v.x; o[1] = (f16)v.y; o[2] = (f16)v.z; o[3] = (f16)v.w;
    *(half4*)&y[i] = o;
}

// Wt[n][k] = (f16) W[k][n].  K,N multiples of 32.  block (32,8)
__global__ __launch_bounds__(256) void transpose_cvt_kernel(const float* __restrict__ W,
                                                            f16* __restrict__ Wt,
                                                            int K, int N) {
    __shared__ float tile[32][33];
    int n0 = blockIdx.x * 32, k0 = blockIdx.y * 32;
    int tx = threadIdx.x, ty = threadIdx.y;
#pragma unroll
    for (int i = 0; i < 32; i += 8)
        tile[ty + i][tx] = W[(size_t)(k0 + ty + i) * N + n0 + tx];
    __syncthreads();
#pragma unroll
    for (int i = 0; i < 32; i += 8)
        Wt[(size_t)(n0 + ty + i) * K + k0 + tx] = (f16)tile[tx][ty + i];
}

// ------------------------------ fp16 MFMA GEMM -----------------------------

__global__ __launch_bounds__(256) void gemm16_kernel(const f16* __restrict__ A,
                                                     const f16* __restrict__ Bt,
                                                     f16* __restrict__ C,
                                                     int N, int K) {
    __shared__ f16 As[128 * 32];
    __shared__ f16 Bs[128 * 32];
    int t = threadIdx.x;
    int w = t >> 6;
    int l = t & 63;
    size_t bm = (size_t)blockIdx.y * 128;
    int bn = blockIdx.x * 128;
    int wm = (w & 1) * 64;
    int wn = (w >> 1) * 64;

    int srow = t >> 2;
    int scol = (t & 3) * 8;
    const f16* ag0 = A + (bm + srow) * K + scol;
    const f16* ag1 = A + (bm + 64 + srow) * K + scol;
    const f16* bg0 = Bt + (size_t)(bn + srow) * K + scol;
    const f16* bg1 = Bt + (size_t)(bn + 64 + srow) * K + scol;
    f16* al0 = As + t * 8;
    f16* al1 = As + 2048 + t * 8;
    f16* bl0 = Bs + t * 8;
    f16* bl1 = Bs + 2048 + t * 8;

    float4v acc[4][4];
#pragma unroll
    for (int i = 0; i < 4; ++i)
#pragma unroll
        for (int j = 0; j < 4; ++j) acc[i][j] = (float4v)(0.f);

    int ml = l & 15, q = l >> 4;
    const f16* ap = As + (wm + ml) * 32 + q * 8;
    const f16* bp = Bs + (wn + ml) * 32 + q * 8;

    for (int k0 = 0; k0 < K; k0 += 32) {
        gload_lds16(ag0 + k0, al0);
        gload_lds16(ag1 + k0, al1);
        gload_lds16(bg0 + k0, bl0);
        gload_lds16(bg1 + k0, bl1);
        __syncthreads();
        half8 af[4], bf[4];
#pragma unroll
        for (int mt = 0; mt < 4; ++mt) af[mt] = *(const half8*)(ap + mt * 16 * 32);
#pragma unroll
        for (int nt = 0; nt < 4; ++nt) bf[nt] = *(const half8*)(bp + nt * 16 * 32);
#pragma unroll
        for (int mt = 0; mt < 4; ++mt)
#pragma unroll
            for (int nt = 0; nt < 4; ++nt)
                acc[mt][nt] = __builtin_amdgcn_mfma_f32_16x16x32_f16(bf[nt], af[mt],
                                                                     acc[mt][nt], 0, 0, 0);
        __syncthreads();
    }
#pragma unroll
    for (int mt = 0; mt < 4; ++mt) {
        size_t row = bm + wm + mt * 16 + ml;
#pragma unroll
        for (int nt = 0; nt < 4; ++nt) {
            half4 hv;
#pragma unroll
            for (int r = 0; r < 4; ++r) hv[r] = (f16)acc[mt][nt][r];
            *(half4*)&C[row * N + bn + wn + nt * 16 + q * 4] = hv;
        }
    }
}

// --------------------------- attention logits ------------------------------

__global__ void attn_logits_kernel(const f16* __restrict__ feat, int fs,
                                   const float* __restrict__ al,
                                   const float* __restrict__ ar,
                                   float* __restrict__ el8, float* __restrict__ er8,
                                   int H) {
    int v = blockIdx.x;
    int h = threadIdx.y;
    int lane = threadIdx.x;
    half2v f2 = *(const half2v*)&feat[(size_t)v * fs + h * 128 + 2 * lane];
    float f0 = (float)f2[0], f1 = (float)f2[1];
    float sl = f0 * al[h * 128 + 2 * lane] + f1 * al[h * 128 + 2 * lane + 1];
    float sr = f0 * ar[h * 128 + 2 * lane] + f1 * ar[h * 128 + 2 * lane + 1];
#pragma unroll
    for (int off = 32; off > 0; off >>= 1) {
        sl += __shfl_down(sl, off, 64);
        sr += __shfl_down(sr, off, 64);
    }
    if (lane == 0) { el8[(size_t)v * 8 + h] = sl; er8[(size_t)v * 8 + h] = sr; }
}

// ------------------ head-fused aggregation, H=4 ----------------------------
// persistent grid-stride; lane owns channels 8*lane..8*lane+7 (head=lane>>4)

__global__ __launch_bounds__(256, 8) void gat_agg4_kernel(
        const f16* __restrict__ feat, const float* __restrict__ el8,
        const float* __restrict__ er8, const int* __restrict__ row_off,
        const int* __restrict__ csr_src, const f16* __restrict__ res,
        const float* __restrict__ bias, f16* __restrict__ out, int n) {
    __shared__ float wls[4][256];
    __shared__ int sls[4][64];
    int wid = threadIdx.x >> 6, lane = threadIdx.x & 63;
    float* wl = wls[wid];
    int* sl = sls[wid];
    int hh = lane >> 4;
    int c0 = lane * 8;
    float4 bv0 = *(const float4*)&bias[c0];
    float4 bv1 = *(const float4*)&bias[c0 + 4];

    for (int v = blockIdx.x * 4 + wid; v < n; v += AGG_WAVES) {
        float4 erv = *(const float4*)&er8[(size_t)v * 8];
        float era[4] = {erv.x, erv.y, erv.z, erv.w};
        int beg = row_off[v], end = row_off[v + 1];
        float acc[8] = {0.f, 0.f, 0.f, 0.f, 0.f, 0.f, 0.f, 0.f};
        float ls[4] = {0.f, 0.f, 0.f, 0.f};

        for (int pos = beg; pos < end; pos += 64) {
            int cnt = min(64, end - pos);
            int s_l = (lane < cnt) ? csr_src[pos + lane] : 0;
            float4 e4 = *(const float4*)&el8[(size_t)s_l * 8];
            float ee[4] = {e4.x, e4.y, e4.z, e4.w};
            float w4[4];
#pragma unroll
            for (int h = 0; h < 4; ++h) {
                float lg = ee[h] + era[h];
                lg = (lg >= 0.f) ? lg : 0.2f * lg;
                float w = __expf(lg);
                if (lane >= cnt) w = 0.f;
                w4[h] = w;
                ls[h] += w;
            }
            sl[lane] = s_l;
            *(float4*)&wl[lane * 4] = make_float4(w4[0], w4[1], w4[2], w4[3]);
#pragma unroll 8
            for (int i = 0; i < cnt; ++i) {
                int s = sl[i];
                float w = wl[i * 4 + hh];
                half8 f = *(const half8*)&feat[(size_t)s * 512 + c0];
#pragma unroll
                for (int j = 0; j < 8; ++j) acc[j] += w * (float)f[j];
            }
        }
#pragma unroll
        for (int h = 0; h < 4; ++h)
#pragma unroll
            for (int off = 32; off >= 1; off >>= 1) ls[h] += __shfl_xor(ls[h], off, 64);
        float lsh = ls[0];
        lsh = (hh == 1) ? ls[1] : lsh;
        lsh = (hh == 2) ? ls[2] : lsh;
        lsh = (hh == 3) ? ls[3] : lsh;
        float inv = 1.f / fmaxf(lsh, 1e-9f);
        size_t base = (size_t)v * 512 + c0;
        float ox[8];
#pragma unroll
        for (int j = 0; j < 8; ++j) ox[j] = acc[j] * inv;
        if (res) {
            half8 r = *(const half8*)&res[base];
#pragma unroll
            for (int j = 0; j < 8; ++j) ox[j] += (float)r[j];
        }
        ox[0] += bv0.x; ox[1] += bv0.y; ox[2] += bv0.z; ox[3] += bv0.w;
        ox[4] += bv1.x; ox[5] += bv1.y; ox[6] += bv1.z; ox[7] += bv1.w;
        half8 o;
#pragma unroll
        for (int j = 0; j < 8; ++j) {
            float t = ox[j];
            t = (t > 0.f) ? t : expm1f(t);   // elu
            o[j] = (f16)t;
        }
        *(half8*)&out[base] = o;
    }
}

// ------------------ head-fused aggregation, H=6 ----------------------------
// feat/res rows have stride 1536 (fused layer-2 GEMM output: [feat|res]).
// lane owns chans 8*lane..8*lane+7 (head lane>>4) and 512+4*lane..+3
// (head 4+(lane>>5)) -> one 16B + one 8B load per edge.

__global__ __launch_bounds__(256, 8) void gat_agg6_kernel(
        const f16* __restrict__ feat, const f16* __restrict__ res,
        const float* __restrict__ el8, const float* __restrict__ er8,
        const int* __restrict__ row_off, const int* __restrict__ csr_src,
        const float* __restrict__ bias, const int* __restrict__ gid,
        float* __restrict__ out_local, float* __restrict__ pooled,
        float* __restrict__ cntbuf, int n) {
    __shared__ float wls[4][64 * 6];
    __shared__ int sls[4][64];
    __shared__ float xbuf[4][768];
    int wid = threadIdx.x >> 6, lane = threadIdx.x & 63;
    float* wl = wls[wid];
    int* sl = sls[wid];
    float* xb = xbuf[wid];
    int ha = lane >> 4;          // 0..3
    int hb = 4 + (lane >> 5);    // 4..5
    int ca = lane * 8;
    int cb = 512 + lane * 4;
    float4 ba0 = *(const float4*)&bias[ca];
    float4 ba1 = *(const float4*)&bias[ca + 4];
    float4 bb0 = *(const float4*)&bias[cb];

    for (int v = blockIdx.x * 4 + wid; v < n; v += AGG_WAVES) {
        float era[6];
        {
            float4 a = *(const float4*)&er8[(size_t)v * 8];
            float2 b = *(const float2*)&er8[(size_t)v * 8 + 4];
            era[0] = a.x; era[1] = a.y; era[2] = a.z; era[3] = a.w;
            era[4] = b.x; era[5] = b.y;
        }
        int beg = row_off[v], end = row_off[v + 1];
        float acc[12];
#pragma unroll
        for (int j = 0; j < 12; ++j) acc[j] = 0.f;
        float ls[6] = {0.f, 0.f, 0.f, 0.f, 0.f, 0.f};

        for (int pos = beg; pos < end; pos += 64) {
            int cnt = min(64, end - pos);
            int s_l = (lane < cnt) ? csr_src[pos + lane] : 0;
            float ee[6];
            {
                float4 a = *(const float4*)&el8[(size_t)s_l * 8];
                float2 b = *(const float2*)&el8[(size_t)s_l * 8 + 4];
                ee[0] = a.x; ee[1] = a.y; ee[2] = a.z; ee[3] = a.w;
                ee[4] = b.x; ee[5] = b.y;
            }
#pragma unroll
            for (int h = 0; h < 6; ++h) {
                float lg = ee[h] + era[h];
                lg = (lg >= 0.f) ? lg : 0.2f * lg;
                float w = __expf(lg);
                if (lane >= cnt) w = 0.f;
                wl[lane * 6 + h] = w;
                ls[h] += w;
            }
            sl[lane] = s_l;
#pragma unroll 4
            for (int i = 0; i < cnt; ++i) {
                int s = sl[i];
                float wa = wl[i * 6 + ha];
                float wb = wl[i * 6 + hb];
                const f16* fp = &feat[(size_t)s * 1536];
                half8 fa = *(const half8*)(fp + ca);
                half4 fb = *(const half4*)(fp + cb);
#pragma unroll
                for (int j = 0; j < 8; ++j) acc[j] += wa * (float)fa[j];
#pragma unroll
                for (int j = 0; j < 4; ++j) acc[8 + j] += wb * (float)fb[j];
            }
        }
#pragma unroll
        for (int h = 0; h < 6; ++h)
#pragma unroll
            for (int off = 32; off >= 1; off >>= 1) ls[h] += __shfl_xor(ls[h], off, 64);
        float lsa = ls[0];
        lsa = (ha == 1) ? ls[1] : lsa;
        lsa = (ha == 2) ? ls[2] : lsa;
        lsa = (ha == 3) ? ls[3] : lsa;
        float lsb = (hb == 5) ? ls[5] : ls[4];
        float iva = 1.f / fmaxf(lsa, 1e-9f);
        float ivb = 1.f / fmaxf(lsb, 1e-9f);
        float ox[12];
#pragma unroll
        for (int j = 0; j < 8; ++j) ox[j] = acc[j] * iva;
#pragma unroll
        for (int j = 0; j < 4; ++j) ox[8 + j] = acc[8 + j] * ivb;
        {
            const f16* rp = &res[(size_t)v * 1536];
            half8 ra = *(const half8*)(rp + ca);
            half4 rb = *(const half4*)(rp + cb);
#pragma unroll
            for (int j = 0; j < 8; ++j) ox[j] += (float)ra[j];
#pragma unroll
            for (int j = 0; j < 4; ++j) ox[8 + j] += (float)rb[j];
        }
        ox[0] += ba0.x; ox[1] += ba0.y; ox[2]  += ba0.z; ox[3]  += ba0.w;
        ox[4] += ba1.x; ox[5] += ba1.y; ox[6]  += ba1.z; ox[7]  += ba1.w;
        ox[8] += bb0.x; ox[9] += bb0.y; ox[10] += bb0.z; ox[11] += bb0.w;
        // no activation; head-mean via LDS transpose
        *(float4*)&xb[ca]     = make_float4(ox[0], ox[1], ox[2], ox[3]);
        *(float4*)&xb[ca + 4] = make_float4(ox[4], ox[5], ox[6], ox[7]);
        *(float4*)&xb[cb]     = make_float4(ox[8], ox[9], ox[10], ox[11]);
        int d0 = 2 * lane;
        float s0 = 0.f, s1 = 0.f;
#pragma unroll
        for (int hh2 = 0; hh2 < 6; ++hh2) {
            s0 += xb[hh2 * 128 + d0];
            s1 += xb[hh2 * 128 + d0 + 1];
        }
        s0 *= (1.f / 6.f);
        s1 *= (1.f / 6.f);
        *(float2*)&out_local[(size_t)v * 128 + d0] = make_float2(s0, s1);
        int g = gid[v];
        atomicAdd(&pooled[g * 128 + d0], s0);
        atomicAdd(&pooled[g * 128 + d0 + 1], s1);
        if (lane == 0) atomicAdd(&cntbuf[g], 1.0f);
    }
}

// ------------------------------ final MLP ----------------------------------

__global__ void final_mlp_kernel(const float* __restrict__ pooled,
                                 const float* __restrict__ cnt,
                                 const float* __restrict__ Wm,
                                 const float* __restrict__ bm,
                                 float* __restrict__ gout) {
    int g = blockIdx.x;
    int j = threadIdx.x;
    __shared__ float p[128];
    float c = fmaxf(cnt[g], 1.0f);
    p[j] = pooled[g * 128 + j] / c;
    __syncthreads();
    float s = 0.f;
#pragma unroll 16
    for (int k = 0; k < 128; ++k) s += p[k] * Wm[k * 128 + j];
    gout[g * 128 + j] = s + bm[j];
}

// --------------------------------- driver ----------------------------------

extern "C" void kernel_launch(void* const* d_in, const int* in_sizes, int n_in,
                              void* d_out, int out_size, void* d_ws, size_t ws_size,
                              hipStream_t stream) {
    const float* h     = (const float*)d_in[0];
    const int*   src   = (const int*)d_in[2];
    const int*   dst   = (const int*)d_in[3];
    const int*   gid   = (const int*)d_in[4];
    const float* W0    = (const float*)d_in[5];
    const float* al0   = (const float*)d_in[6];
    const float* ar0   = (const float*)d_in[7];
    const float* b0    = (const float*)d_in[8];
    const float* W1    = (const float*)d_in[9];
    const float* al1   = (const float*)d_in[10];
    const float* ar1   = (const float*)d_in[11];
    const float* b1    = (const float*)d_in[12];
    const float* W2    = (const float*)d_in[13];
    const float* al2   = (const float*)d_in[14];
    const float* ar2   = (const float*)d_in[15];
    const float* b2    = (const float*)d_in[16];
    const float* resW2 = (const float*)d_in[17];
    const float* Wm    = (const float*)d_in[18];
    const float* bm    = (const float*)d_in[19];

    const int n = in_sizes[0] / 128;   // 20000
    const int E = in_sizes[2];         // 320000

    size_t off = 0;
    auto take = [&](size_t bytes) -> void* {
        void* p = (char*)d_ws + off;
        off = (off + bytes + 255) & ~(size_t)255;
        return p;
    };
    f16* h16     = (f16*)take((size_t)M_PAD * 128 * 2);
    f16* Wt0     = (f16*)take((size_t)512 * 128 * 2);
    f16* Wt1     = (f16*)take((size_t)512 * 512 * 2);
    f16* Wt2cat  = (f16*)take((size_t)1536 * 512 * 2);  // [W2^T ; resW2^T]
    f16* featC   = (f16*)take((size_t)M_PAD * 1536 * 2); // layer feats (and [feat|res] for L2)
    f16* x1_16   = (f16*)take((size_t)M_PAD * 512 * 2);
    f16* x2_16   = (f16*)take((size_t)M_PAD * 512 * 2);
    float* el8   = (float*)take((size_t)n * 8 * 4);
    float* er8   = (float*)take((size_t)n * 8 * 4);
    int* deg     = (int*)take((size_t)n * 4);
    int* row_off = (int*)take((size_t)(n + 1) * 4);
    int* fillc   = (int*)take((size_t)n * 4);
    int* csr_src = (int*)take((size_t)E * 4);
    float* pooled = (float*)take(64 * 128 * 4);
    float* cnt    = (float*)take(64 * 4);

    float* out_local  = (float*)d_out;
    float* out_global = (float*)d_out + (size_t)n * 128;

    hipMemsetAsync(deg, 0, (size_t)n * 4, stream);
    hipMemsetAsync(fillc, 0, (size_t)n * 4, stream);
    hipMemsetAsync(pooled, 0, 64 * 128 * 4, stream);
    hipMemsetAsync(cnt, 0, 64 * 4, stream);
    hipMemsetAsync(x1_16 + (size_t)n * 512, 0, (size_t)(M_PAD - n) * 512 * 2, stream);
    hipMemsetAsync(x2_16 + (size_t)n * 512, 0, (size_t)(M_PAD - n) * 512 * 2, stream);

    {
        long nv = (long)n * 128, nt = (long)M_PAD * 128;
        cvt_pad_kernel<<<(int)((nt / 4 + 255) / 256), 256, 0, stream>>>(h, h16, nv, nt);
    }
    transpose_cvt_kernel<<<dim3(512 / 32, 128 / 32), dim3(32, 8), 0, stream>>>(W0, Wt0, 128, 512);
    transpose_cvt_kernel<<<dim3(512 / 32, 512 / 32), dim3(32, 8), 0, stream>>>(W1, Wt1, 512, 512);
    transpose_cvt_kernel<<<dim3(768 / 32, 512 / 32), dim3(32, 8), 0, stream>>>(W2, Wt2cat, 512, 768);
    transpose_cvt_kernel<<<dim3(768 / 32, 512 / 32), dim3(32, 8), 0, stream>>>(resW2, Wt2cat + (size_t)768 * 512, 512, 768);

    deg_kernel<<<(E + 255) / 256, 256, 0, stream>>>(dst, deg, E);
    scan_kernel<<<1, 1024, 0, stream>>>(deg, row_off, n);
    fill_kernel<<<(E + 255) / 256, 256, 0, stream>>>(src, dst, row_off, fillc, csr_src, E);

    const int gy = M_PAD / 128;

    // --- layer 0: feat = h16 @ W0 (N=512), H=4, no res, elu ---
    gemm16_kernel<<<dim3(512 / 128, gy), 256, 0, stream>>>(h16, Wt0, featC, 512, 128);
    attn_logits_kernel<<<n, dim3(64, 4), 0, stream>>>(featC, 512, al0, ar0, el8, er8, 4);
    gat_agg4_kernel<<<AGG_BLOCKS, 256, 0, stream>>>(featC, el8, er8, row_off, csr_src,
                                                    nullptr, b0, x1_16, n);
    // --- layer 1: feat = x1 @ W1 (N=512), H=4, identity res, elu ---
    gemm16_kernel<<<dim3(512 / 128, gy), 256, 0, stream>>>(x1_16, Wt1, featC, 512, 512);
    attn_logits_kernel<<<n, dim3(64, 4), 0, stream>>>(featC, 512, al1, ar1, el8, er8, 4);
    gat_agg4_kernel<<<AGG_BLOCKS, 256, 0, stream>>>(featC, el8, er8, row_off, csr_src,
                                                    x1_16, b1, x2_16, n);
    // --- layer 2: [feat|res] = x2 @ [W2|resW2] (N=1536), H=6, no act ---
    gemm16_kernel<<<dim3(1536 / 128, gy), 256, 0, stream>>>(x2_16, Wt2cat, featC, 1536, 512);
    attn_logits_kernel<<<n, dim3(64, 6), 0, stream>>>(featC, 1536, al2, ar2, el8, er8, 6);
    gat_agg6_kernel<<<AGG_BLOCKS, 256, 0, stream>>>(featC, featC + 768, el8, er8, row_off,
                                                    csr_src, b2, gid, out_local, pooled, cnt, n);
    // --- pooling epilogue ---
    final_mlp_kernel<<<64, 128, 0, stream>>>(pooled, cnt, Wm, bm, out_global);
}